// Round 15
// baseline (350.524 us; speedup 1.0000x reference)
//
#include <hip/hip_runtime.h>
#include <hip/hip_bf16.h>

typedef __hip_bfloat16 bf16t;
using f32x4 = __attribute__((ext_vector_type(4))) float;
using s16x8 = __attribute__((ext_vector_type(8))) short;

#define NTOK 4096
#define DIM 1024
#define HID 2048
#define NEXP 8
#define NMODE 4
#define NGRP 13
#define SLOTS_PAD 16640   // 16384 + 256 pad for partial tiles
#define MAXT 144          // 128-row tiles over all groups (<=141)

// ---------------- workspace layout (bytes) ----------------
static constexpr size_t SZ_WT    = (size_t)NGRP * HID * DIM * 2;   // 54,525,952
static constexpr size_t OFF_WT1  = 0;
static constexpr size_t OFF_OBUF = 0;                               // overlay: WT1 dead before GEMM2
static constexpr size_t OFF_WT2  = OFF_WT1 + SZ_WT;
static constexpr size_t OFF_HBUF = OFF_WT2 + SZ_WT;
static constexpr size_t SZ_HBUF  = (size_t)SLOTS_PAD * HID * 2;
static constexpr size_t OFF_XBF  = OFF_HBUF + SZ_HBUF;
static constexpr size_t SZ_XBF   = (size_t)NTOK * DIM * 2;
static constexpr size_t OFF_B1   = OFF_XBF + SZ_XBF;
static constexpr size_t OFF_B2   = OFF_B1 + (size_t)NGRP * HID * 4;
static constexpr size_t OFF_TP   = OFF_B2 + (size_t)NGRP * DIM * 4;
static constexpr size_t OFF_TI   = OFF_TP + (size_t)NTOK * 2 * 4;
static constexpr size_t OFF_MS   = OFF_TI + (size_t)NTOK * 2 * 4;
static constexpr size_t OFF_R0S  = OFF_MS + (size_t)NTOK * 4;
static constexpr size_t OFF_R1S  = OFF_R0S + (size_t)NTOK * 4;
static constexpr size_t OFF_LIST = OFF_R1S + (size_t)NTOK * 4;
static constexpr size_t OFF_CUR  = OFF_LIST + (size_t)SLOTS_PAD * 4;
static constexpr size_t OFF_TC   = OFF_CUR + 64;
static constexpr size_t OFF_TD   = OFF_TC + 16;
static constexpr size_t WS_NEED  = OFF_TD + (size_t)MAXT * 16;

static __device__ __forceinline__ short fb(float f) {
    bf16t h = __float2bfloat16(f);
    short s; __builtin_memcpy(&s, &h, 2); return s;
}
static __device__ __forceinline__ float bf2f(short s) {
    unsigned u = ((unsigned)(unsigned short)s) << 16;
    float f; __builtin_memcpy(&f, &u, 4); return f;
}

static __device__ __forceinline__ float fast_exp(float x) {
#if __has_builtin(__builtin_amdgcn_exp2f)
    return __builtin_amdgcn_exp2f(x * 1.4426950408889634f);
#else
    return exp2f(x * 1.4426950408889634f);
#endif
}
static __device__ __forceinline__ float fast_rcp(float x) {
#if __has_builtin(__builtin_amdgcn_rcpf)
    return __builtin_amdgcn_rcpf(x);
#else
    return 1.0f / x;
#endif
}
static __device__ __forceinline__ float gelu_tanh(float x) {
    float x2 = x * x;
    float u = 0.7978845608028654f * fmaf(0.044715f * x2, x, x);
    u = fminf(u, 15.0f);
    float t = fast_exp(2.0f * u);
    return x * t * fast_rcp(t + 1.0f);
}

typedef __attribute__((address_space(3))) void lds_void;
typedef const __attribute__((address_space(1))) void gbl_void;
static __device__ __forceinline__ void gload16(const void* g, void* l) {
    __builtin_amdgcn_global_load_lds((gbl_void*)g, (lds_void*)l, 16, 0, 0);
}

struct TPtr {
    const float* s_w1; const float* s_w2;
    const float* m_w1; const float* m_w2;
    const float* r_w1; const float* r_w2;
};

// 64x128 transpose+convert unit. smem >= 2*64*65*4 B. x = col-tile, y = row-pair.
static __device__ __forceinline__ void transpose_tile(
    const float* __restrict__ src, bf16t* __restrict__ dst, int R, int C, int x, int y,
    float (*lds)[64][65], int t) {
    const int c0 = x * 64;
    const int ar = t >> 4, ac = (t & 15) * 4;
    const int bc = t >> 3;
    const int rg = (t & 7) * 8;
#pragma unroll
    for (int it = 0; it < 2; ++it) {
        const int r0 = (y * 2 + it) * 64;
#pragma unroll
        for (int p = 0; p < 4; p++) {
            const int r = p * 16 + ar;
            const float4 v = *(const float4*)(src + (size_t)(r0 + r) * C + (c0 + ac));
            lds[it][r][ac] = v.x; lds[it][r][ac + 1] = v.y;
            lds[it][r][ac + 2] = v.z; lds[it][r][ac + 3] = v.w;
        }
    }
    __syncthreads();
#pragma unroll
    for (int it = 0; it < 2; ++it) {
        const int r0 = (y * 2 + it) * 64;
#pragma unroll
        for (int j = 0; j < 2; j++) {
            const int c = j * 32 + bc;
            unsigned w[4];
#pragma unroll
            for (int u = 0; u < 4; u++) {
                unsigned lo = (unsigned short)fb(lds[it][rg + 2 * u][c]);
                unsigned hi = (unsigned short)fb(lds[it][rg + 2 * u + 1][c]);
                w[u] = (hi << 16) | lo;
            }
            *(uint4*)((char*)dst + ((size_t)(c0 + c) * R + (r0 + rg)) * 2) = make_uint4(w[0], w[1], w[2], w[3]);
        }
    }
}

// ================= fused prep: W1 transpose || router+xconv || biascat =================
#define TGRID1 3328
#define RGRID  4352
#define PGRID  4456

__global__ __launch_bounds__(256) void prep_k(
    TPtr tp, bf16t* __restrict__ wt1,
    const float* __restrict__ hidden, const int* __restrict__ mode_ids,
    const float* __restrict__ rw, const float* __restrict__ rb,
    float* __restrict__ aux_logits, float* __restrict__ aux_idx, float* __restrict__ aux_probs,
    float* __restrict__ topk_p, int* __restrict__ topk_i, bf16t* __restrict__ xbf,
    const float* __restrict__ sb1, const float* __restrict__ mb1, const float* __restrict__ rb1,
    const float* __restrict__ sb2, const float* __restrict__ mb2, const float* __restrict__ rb2,
    float* __restrict__ B1c, float* __restrict__ B2c) {
    const int bid = blockIdx.x;
    const int t = threadIdx.x;

    if (bid < TGRID1) {
        __shared__ float lds[2][64][65];
        const size_t MSZ = (size_t)DIM * HID;
        const int z = bid >> 8, rem = bid & 255;
        const int x = (rem >> 3) & 31, y = rem & 7;     // 32 col-tiles x 8 row-pairs
        const float* src;
        if (z == 0)      src = tp.s_w1;
        else if (z < 5)  src = tp.m_w1 + (size_t)(z - 1) * MSZ;
        else             src = tp.r_w1 + (size_t)(z - 5) * MSZ;
        transpose_tile(src, wt1 + (size_t)z * MSZ, DIM, HID, x, y, lds, t);
        return;
    }

    if (bid < RGRID) {
        // ---------------- router: 4 tokens/block + fused f32->bf16 convert ----------------
        const int tok = (bid - TGRID1) * 4 + (t >> 6);
        const int lane = t & 63;
        const float* x = hidden + (size_t)tok * DIM;
        float acc[NEXP];
#pragma unroll
        for (int e = 0; e < NEXP; e++) acc[e] = 0.f;
#pragma unroll
        for (int i = 0; i < DIM / 64; i++) {
            int d = i * 64 + lane;
            float xv = x[d];
            xbf[(size_t)tok * DIM + d] = __float2bfloat16(xv);
            const float4* w = (const float4*)(rw + (size_t)d * NEXP);
            float4 w0 = w[0], w1 = w[1];
            acc[0] += xv * w0.x; acc[1] += xv * w0.y; acc[2] += xv * w0.z; acc[3] += xv * w0.w;
            acc[4] += xv * w1.x; acc[5] += xv * w1.y; acc[6] += xv * w1.z; acc[7] += xv * w1.w;
        }
#pragma unroll
        for (int off = 32; off >= 1; off >>= 1) {
#pragma unroll
            for (int e = 0; e < NEXP; e++) acc[e] += __shfl_down(acc[e], off, 64);
        }
        if (lane == 0) {
            float lg[NEXP], pb[NEXP];
            float mx = -1e30f;
#pragma unroll
            for (int e = 0; e < NEXP; e++) { lg[e] = acc[e] + rb[e]; mx = fmaxf(mx, lg[e]); }
            float s = 0.f;
#pragma unroll
            for (int e = 0; e < NEXP; e++) { pb[e] = expf(lg[e] - mx); s += pb[e]; }
            float inv = 1.f / s;
#pragma unroll
            for (int e = 0; e < NEXP; e++) { pb[e] *= inv; aux_logits[(size_t)tok * NEXP + e] = lg[e]; }
            int i1 = 0;
            for (int e = 1; e < NEXP; e++) if (pb[e] > pb[i1]) i1 = e;
            int i2 = (i1 == 0) ? 1 : 0;
            for (int e = 0; e < NEXP; e++) { if (e == i1) continue; if (pb[e] > pb[i2]) i2 = e; }
            aux_idx[tok * 2] = (float)i1;  aux_idx[tok * 2 + 1] = (float)i2;
            aux_probs[tok * 2] = pb[i1];   aux_probs[tok * 2 + 1] = pb[i2];
            topk_p[tok * 2] = pb[i1];      topk_p[tok * 2 + 1] = pb[i2];
            topk_i[tok * 2] = i1;          topk_i[tok * 2 + 1] = i2;
        }
        return;
    }

    // ---------------- biascat ----------------
    {
        const int i = (bid - RGRID) * 256 + t;
        if (i < NGRP * HID) {
            int g = i / HID, h = i % HID;
            B1c[i] = (g == 0) ? sb1[h] : (g < 5) ? mb1[(g - 1) * HID + h] : rb1[(g - 5) * HID + h];
        }
        if (i < NGRP * DIM) {
            int g = i / DIM, d = i % DIM;
            B2c[i] = (g == 0) ? sb2[d] : (g < 5) ? mb2[(g - 1) * DIM + d] : rb2[(g - 5) * DIM + d];
        }
    }
}

// ------- fused count+scan (single block, 1024 thr): ballot histogram -> cursors+tdesc; zero list pad -------
__global__ __launch_bounds__(1024) void group_k(
    const int* __restrict__ mode_ids, const int* __restrict__ topki,
    int* __restrict__ cursors, int4* __restrict__ tdesc, int* __restrict__ tcount,
    int* __restrict__ list) {
    __shared__ int cnts[12];
    const int lane = threadIdx.x & 63;
    const int wave = threadIdx.x >> 6;   // 0..15
    if (threadIdx.x < 12) cnts[threadIdx.x] = 0;
    // zero list pad [16384, SLOTS_PAD)
    if (threadIdx.x < SLOTS_PAD - 16384) list[16384 + threadIdx.x] = 0;
    __syncthreads();
    int local[12];
#pragma unroll
    for (int i = 0; i < 12; i++) local[i] = 0;
#pragma unroll
    for (int c = wave; c < NTOK / 64; c += 16) {
        const int t = c * 64 + lane;
        const int m  = mode_ids[t];
        const int e0 = topki[t * 2];
        const int e1 = topki[t * 2 + 1];
#pragma unroll
        for (int b = 0; b < 4; b++) local[b] += __popcll(__ballot(m == b));
#pragma unroll
        for (int b = 0; b < 8; b++) {
            local[4 + b] += __popcll(__ballot(e0 == b));
            local[4 + b] += __popcll(__ballot(e1 == b));
        }
    }
    if (lane == 0) {
#pragma unroll
        for (int i = 0; i < 12; i++) if (local[i]) atomicAdd(&cnts[i], local[i]);
    }
    __syncthreads();
    if (threadIdx.x == 0) {
        int nt = 0;
        auto emit = [&](int off, int c, int g) {
            for (int r0 = 0; r0 < c; r0 += 128) tdesc[nt++] = make_int4(off + r0, min(128, c - r0), g, 0);
        };
        emit(0, NTOK, 0);
        int off = NTOK;
        for (int m = 0; m < NMODE; m++) { cursors[m] = off; emit(off, cnts[m], 1 + m); off += cnts[m]; }
        off = 2 * NTOK;
        for (int e = 0; e < NEXP; e++) { cursors[NMODE + e] = off; emit(off, cnts[NMODE + e], 5 + e); off += cnts[NMODE + e]; }
        tcount[0] = nt;
    }
}

// ---------------- fill slot lists + inverse maps (wave-aggregated atomics) ----------------
__global__ void fill_k(const int* __restrict__ mode_ids, const int* __restrict__ topk_i,
                       int* __restrict__ cursors, int* __restrict__ list,
                       int* __restrict__ ms, int* __restrict__ r0s, int* __restrict__ r1s) {
    const int t = blockIdx.x * 256 + threadIdx.x;
    const int lane = threadIdx.x & 63;
    list[t] = t << 1;                                 // shared: identity
    const int m  = mode_ids[t];
    const int e0 = topk_i[t * 2], e1 = topk_i[t * 2 + 1];

    auto put = [&](int bin, bool pred, int payload, int* inv) {
        unsigned long long msk = __ballot(pred);
        if (msk == 0ull) return;
        int leader = __ffsll((unsigned long long)msk) - 1;
        int base = 0;
        if (lane == leader) base = atomicAdd(&cursors[bin], __popcll(msk));
        base = __shfl(base, leader, 64);
        if (pred) {
            int pos = base + __popcll(msk & ((1ull << lane) - 1ull));
            list[pos] = payload;
            inv[t] = pos;
        }
    };
#pragma unroll
    for (int b = 0; b < NMODE; b++) put(b, m == b, t << 1, ms);
#pragma unroll
    for (int b = 0; b < NEXP; b++) put(NMODE + b, e0 == b, t << 1, r0s);
#pragma unroll
    for (int b = 0; b < NEXP; b++) put(NMODE + b, e1 == b, (t << 1) | 1, r1s);
}

// ------- grouped FFN GEMM: 128x128 tile, BK=32, 4 waves, As ring-2 + Bs ring-3 = 40KB LDS,
//         4 blocks/CU, counted vmcnt(2), 1 barrier/K-tile. STAGE 1 carries W2-transpose
//         tail jobs (bid >= NWG) that backfill GEMM1's drain rounds. -------
// STAGE 1: Hbuf[slot] = gelu(Xbf[tok] @ W1[g] + b1[g])   K=1024, NK=32
// STAGE 2: Obuf[slot] = Hbuf[slot] @ W2[g] + b2[g]       K=2048, NK=64
#define W2GRID 3328
template <int STAGE>
__global__ __launch_bounds__(256, 4) void ffn_gemm_k(
    const bf16t* __restrict__ xbf,
    const bf16t* __restrict__ hbuf,
    const bf16t* __restrict__ wt,
    const float* __restrict__ bias,
    bf16t* __restrict__ obuf,
    const int* __restrict__ list,
    const int4* __restrict__ tdesc,
    const int* __restrict__ tcount,
    const float* __restrict__ w2s, const float* __restrict__ w2m, const float* __restrict__ w2r,
    bf16t* __restrict__ wt2o) {
    constexpr int K   = (STAGE == 1) ? DIM : HID;
    constexpr int N   = (STAGE == 1) ? HID : DIM;
    constexpr int NK  = K / 32;
    constexpr int NTN = N / 128;
    constexpr int NWG = NTN * MAXT;        // 2304 / 1152, divisible by 8

    __shared__ alignas(16) char smem[40960];   // GEMM: As ring-2 (16K) | Bs ring-3 (24K); transpose: 33280B f32 tiles

    if constexpr (STAGE == 1) {
        if (blockIdx.x >= NWG) {
            // ---- W2 transpose tail job (backfills GEMM1 drain) ----
            const int id2 = blockIdx.x - NWG;
            const size_t MSZ = (size_t)DIM * HID;
            const int z = id2 >> 8, rem = id2 & 255;
            const int x = rem >> 4, y = rem & 15;       // 16 col-tiles x 16 row-pairs
            const float* src;
            if (z == 0)      src = w2s;
            else if (z < 5)  src = w2m + (size_t)(z - 1) * MSZ;
            else             src = w2r + (size_t)(z - 5) * MSZ;
            transpose_tile(src, wt2o + (size_t)z * MSZ, HID, DIM, x, y,
                           (float (*)[64][65])smem, threadIdx.x);
            return;
        }
    }

    char* As = smem;                 // 2 * 8192
    char* Bs = smem + 16384;         // 3 * 8192

    const int lin = blockIdx.x;
    const int wg  = (lin & 7) * (NWG >> 3) + (lin >> 3);   // bijective XCD swizzle
    const int ntile = wg / MAXT;
    const int tix = wg - ntile * MAXT;
    if (tix >= tcount[0]) return;
    const int4 td = tdesc[tix];
    const int slot0 = td.x, rows = td.y, gidx = td.z;
    const int n0 = ntile * 128;

    const int tid  = threadIdx.x;    // 0..255
    const int lane = tid & 63;
    const int w    = tid >> 6;       // wave 0..3
    const int wm   = w >> 1, wn = w & 1;   // 2x2 wave grid, each 64x64 out

    // staging: wave w, load h in {0,1} covers 16 rows (w*2+h)*16 .. +16;
    // lane -> row +(lane>>2), chunk lane&3; source chunk inverse-swizzled.
    const bf16t* wbase = wt + (size_t)gidx * ((size_t)K * N);
    const bf16t* aP[2];
    const bf16t* bP[2];
#pragma unroll
    for (int h = 0; h < 2; h++) {
        const int r  = (w * 2 + h) * 16 + (lane >> 2);
        const int ce = (((lane & 3) ^ ((r >> 1) & 3)) << 3);
        if (STAGE == 1) aP[h] = xbf + (size_t)(list[slot0 + r] >> 1) * DIM + ce;
        else            aP[h] = hbuf + (size_t)(slot0 + r) * HID + ce;
        bP[h] = wbase + (size_t)(n0 + r) * K + ce;
    }

    auto stageA = [&](int t) {
        char* la = As + (t & 1) * 8192 + (w * 2) * 1024 + lane * 16;
        gload16(aP[0] + t * 32, la);
        gload16(aP[1] + t * 32, la + 1024);
    };
    auto stageB = [&](int t) {
        char* lb = Bs + (t % 3) * 8192 + (w * 2) * 1024 + lane * 16;
        gload16(bP[0] + t * 32, lb);
        gload16(bP[1] + t * 32, lb + 1024);
    };

    f32x4 acc[4][4];
    const f32x4 zero = {0.f, 0.f, 0.f, 0.f};
#pragma unroll
    for (int i = 0; i < 4; i++)
#pragma unroll
        for (int j = 0; j < 4; j++) acc[i][j] = zero;

    const int lm = lane & 15;
    const int kc = lane >> 4;        // 16B chunk within 64B row

    // prologue: A(0),B(0) then B(1) — queue [A0,B0,B1]
    stageA(0); stageB(0); stageB(1);

    for (int t = 0; t < NK; ++t) {
        const int curA = t & 1;
        const int curB = t % 3;
        // steady-state queue at top: [B(t), A(t), B(t+1)] -> wait <=2: B(t),A(t) done
        if (t + 1 < NK) asm volatile("s_waitcnt vmcnt(2)" ::: "memory");
        else            asm volatile("s_waitcnt vmcnt(0)" ::: "memory");
        __builtin_amdgcn_s_barrier();    // buffers resident for all waves; closes prior reads (WAR)

        s16x8 av[4], bv[4];
#pragma unroll
        for (int i = 0; i < 4; i++) {
            const int Ra = wm * 64 + i * 16 + lm;
            av[i] = *(const s16x8*)(As + curA * 8192 + Ra * 64 + ((kc ^ ((Ra >> 1) & 3)) << 4));
            const int Rb = wn * 64 + i * 16 + lm;
            bv[i] = *(const s16x8*)(Bs + curB * 8192 + Rb * 64 + ((kc ^ ((Rb >> 1) & 3)) << 4));
        }
        if (t + 1 < NK) stageA(t + 1);   // depth-1 A prefetch (ring-2)
        if (t + 2 < NK) stageB(t + 2);   // depth-2 B prefetch (ring-3)

        __builtin_amdgcn_s_setprio(1);
#pragma unroll
        for (int mi = 0; mi < 4; mi++)
#pragma unroll
            for (int ni = 0; ni < 4; ni++)
                acc[mi][ni] = __builtin_amdgcn_mfma_f32_16x16x32_bf16(av[mi], bv[ni], acc[mi][ni], 0, 0, 0);
        __builtin_amdgcn_s_setprio(0);
    }

    const int lr = lane >> 4, lc = lane & 15;
#pragma unroll
    for (int ni = 0; ni < 4; ni++) {
        const int col = n0 + wn * 64 + ni * 16 + lc;
        const float bvv = bias[gidx * N + col];
#pragma unroll
        for (int mi = 0; mi < 4; mi++) {
#pragma unroll
            for (int r = 0; r < 4; r++) {
                const int row = wm * 64 + mi * 16 + lr * 4 + r;
                if (row < rows) {
                    float v = acc[mi][ni][r] + bvv;
                    if (STAGE == 1) v = gelu_tanh(v);
                    obuf[(size_t)(slot0 + row) * N + col] = __float2bfloat16(v);
                }
            }
        }
    }
}

// ---------------- final gather-reduce: out[t] = sh + mode + p0*r0 + p1*r1 ----------------
__global__ void reduce_k(const bf16t* __restrict__ ob,
                         const int* __restrict__ ms, const int* __restrict__ r0s, const int* __restrict__ r1s,
                         const float* __restrict__ topkp, float* __restrict__ out) {
    const int t = blockIdx.x * 4 + (threadIdx.x >> 7);
    const int d = (threadIdx.x & 127) * 8;
    const s16x8 a = *(const s16x8*)(ob + (size_t)t * DIM + d);
    const s16x8 b = *(const s16x8*)(ob + (size_t)ms[t] * DIM + d);
    const s16x8 c = *(const s16x8*)(ob + (size_t)r0s[t] * DIM + d);
    const s16x8 e = *(const s16x8*)(ob + (size_t)r1s[t] * DIM + d);
    const float p0 = topkp[t * 2], p1 = topkp[t * 2 + 1];
    float o[8];
#pragma unroll
    for (int j = 0; j < 8; j++)
        o[j] = bf2f(a[j]) + bf2f(b[j]) + p0 * bf2f(c[j]) + p1 * bf2f(e[j]);
    float* dst = out + (size_t)t * DIM + d;
    *(float4*)dst = make_float4(o[0], o[1], o[2], o[3]);
    *(float4*)(dst + 4) = make_float4(o[4], o[5], o[6], o[7]);
}

extern "C" void kernel_launch(void* const* d_in, const int* in_sizes, int n_in,
                              void* d_out, int out_size, void* d_ws, size_t ws_size,
                              hipStream_t stream) {
    (void)in_sizes; (void)n_in; (void)out_size;
    if (ws_size < WS_NEED) return;

    const float* hidden   = (const float*)d_in[0];
    const int*   mode_ids = (const int*)d_in[1];
    const float* router_w = (const float*)d_in[2];
    const float* router_b = (const float*)d_in[3];
    TPtr tp;
    tp.s_w1 = (const float*)d_in[4];
    const float* s_b1 = (const float*)d_in[5];
    tp.s_w2 = (const float*)d_in[6];
    const float* s_b2 = (const float*)d_in[7];
    tp.m_w1 = (const float*)d_in[8];
    const float* m_b1 = (const float*)d_in[9];
    tp.m_w2 = (const float*)d_in[10];
    const float* m_b2 = (const float*)d_in[11];
    tp.r_w1 = (const float*)d_in[12];
    const float* r_b1 = (const float*)d_in[13];
    tp.r_w2 = (const float*)d_in[14];
    const float* r_b2 = (const float*)d_in[15];

    char* ws = (char*)d_ws;
    bf16t* WT1   = (bf16t*)(ws + OFF_WT1);
    bf16t* WT2   = (bf16t*)(ws + OFF_WT2);
    bf16t* Hbuf  = (bf16t*)(ws + OFF_HBUF);
    bf16t* Xbf   = (bf16t*)(ws + OFF_XBF);
    bf16t* Obuf  = (bf16t*)(ws + OFF_OBUF);
    float* B1c   = (float*)(ws + OFF_B1);
    float* B2c   = (float*)(ws + OFF_B2);
    float* topkp = (float*)(ws + OFF_TP);
    int*   topki = (int*)(ws + OFF_TI);
    int*   ms    = (int*)(ws + OFF_MS);
    int*   r0s   = (int*)(ws + OFF_R0S);
    int*   r1s   = (int*)(ws + OFF_R1S);
    int*   list  = (int*)(ws + OFF_LIST);
    int*   curs  = (int*)(ws + OFF_CUR);
    int*   tcnt  = (int*)(ws + OFF_TC);
    int4*  td    = (int4*)(ws + OFF_TD);

    float* out        = (float*)d_out;
    float* aux_logits = out + (size_t)NTOK * DIM;
    float* aux_idx    = aux_logits + (size_t)NTOK * NEXP;
    float* aux_probs  = aux_idx + (size_t)NTOK * 2;

    prep_k<<<PGRID, 256, 0, stream>>>(tp, WT1,
                                      hidden, mode_ids, router_w, router_b,
                                      aux_logits, aux_idx, aux_probs, topkp, topki, Xbf,
                                      s_b1, m_b1, r_b1, s_b2, m_b2, r_b2, B1c, B2c);
    group_k<<<1, 1024, 0, stream>>>(mode_ids, topki, curs, td, tcnt, list);
    fill_k<<<NTOK / 256, 256, 0, stream>>>(mode_ids, topki, curs, list, ms, r0s, r1s);
    ffn_gemm_k<1><<<(HID / 128) * MAXT + W2GRID, 256, 0, stream>>>(
        Xbf, Hbuf, WT1, B1c, Hbuf, list, td, tcnt, tp.s_w2, tp.m_w2, tp.r_w2, WT2);
    ffn_gemm_k<2><<<(DIM / 128) * MAXT, 256, 0, stream>>>(
        Xbf, Hbuf, WT2, B2c, Obuf, list, td, tcnt, nullptr, nullptr, nullptr, nullptr);
    reduce_k<<<NTOK / 4, 512, 0, stream>>>(Obuf, ms, r0s, r1s, topkp, out);
}

// Round 16
// 336.473 us; speedup vs baseline: 1.0418x; 1.0418x over previous
//
#include <hip/hip_runtime.h>
#include <hip/hip_bf16.h>

typedef __hip_bfloat16 bf16t;
using f32x4 = __attribute__((ext_vector_type(4))) float;
using s16x8 = __attribute__((ext_vector_type(8))) short;

#define NTOK 4096
#define DIM 1024
#define HID 2048
#define NEXP 8
#define NMODE 4
#define NGRP 13
#define SLOTS_PAD 16640   // 16384 + 256 pad for partial tiles
#define MAXT 144          // 128-row tiles over all groups (<=141)

// ---------------- workspace layout (bytes) ----------------
static constexpr size_t SZ_WT    = (size_t)NGRP * HID * DIM * 2;   // 54,525,952
static constexpr size_t OFF_WT1  = 0;
static constexpr size_t OFF_OBUF = 0;                               // overlay: WT1 dead before GEMM2
static constexpr size_t OFF_WT2  = OFF_WT1 + SZ_WT;
static constexpr size_t OFF_HBUF = OFF_WT2 + SZ_WT;
static constexpr size_t SZ_HBUF  = (size_t)SLOTS_PAD * HID * 2;
static constexpr size_t OFF_XBF  = OFF_HBUF + SZ_HBUF;
static constexpr size_t SZ_XBF   = (size_t)NTOK * DIM * 2;
static constexpr size_t OFF_B1   = OFF_XBF + SZ_XBF;
static constexpr size_t OFF_B2   = OFF_B1 + (size_t)NGRP * HID * 4;
static constexpr size_t OFF_TP   = OFF_B2 + (size_t)NGRP * DIM * 4;
static constexpr size_t OFF_TI   = OFF_TP + (size_t)NTOK * 2 * 4;
static constexpr size_t OFF_MS   = OFF_TI + (size_t)NTOK * 2 * 4;
static constexpr size_t OFF_R0S  = OFF_MS + (size_t)NTOK * 4;
static constexpr size_t OFF_R1S  = OFF_R0S + (size_t)NTOK * 4;
static constexpr size_t OFF_LIST = OFF_R1S + (size_t)NTOK * 4;
static constexpr size_t OFF_CUR  = OFF_LIST + (size_t)SLOTS_PAD * 4;
static constexpr size_t OFF_TC   = OFF_CUR + 64;
static constexpr size_t OFF_TD   = OFF_TC + 16;
static constexpr size_t WS_NEED  = OFF_TD + (size_t)MAXT * 16;

static __device__ __forceinline__ short fb(float f) {
    bf16t h = __float2bfloat16(f);
    short s; __builtin_memcpy(&s, &h, 2); return s;
}
static __device__ __forceinline__ float bf2f(short s) {
    unsigned u = ((unsigned)(unsigned short)s) << 16;
    float f; __builtin_memcpy(&f, &u, 4); return f;
}

static __device__ __forceinline__ float fast_exp(float x) {
#if __has_builtin(__builtin_amdgcn_exp2f)
    return __builtin_amdgcn_exp2f(x * 1.4426950408889634f);
#else
    return exp2f(x * 1.4426950408889634f);
#endif
}
static __device__ __forceinline__ float fast_rcp(float x) {
#if __has_builtin(__builtin_amdgcn_rcpf)
    return __builtin_amdgcn_rcpf(x);
#else
    return 1.0f / x;
#endif
}
static __device__ __forceinline__ float gelu_tanh(float x) {
    float x2 = x * x;
    float u = 0.7978845608028654f * fmaf(0.044715f * x2, x, x);
    u = fminf(u, 15.0f);
    float t = fast_exp(2.0f * u);
    return x * t * fast_rcp(t + 1.0f);
}

typedef __attribute__((address_space(3))) void lds_void;
typedef const __attribute__((address_space(1))) void gbl_void;
static __device__ __forceinline__ void gload16(const void* g, void* l) {
    __builtin_amdgcn_global_load_lds((gbl_void*)g, (lds_void*)l, 16, 0, 0);
}

struct TPtr {
    const float* s_w1; const float* s_w2;
    const float* m_w1; const float* m_w2;
    const float* r_w1; const float* r_w2;
};

// 64x128 transpose+convert unit. smem >= 2*64*65*4 B. x = col-tile, y = row-pair.
static __device__ __forceinline__ void transpose_tile(
    const float* __restrict__ src, bf16t* __restrict__ dst, int R, int C, int x, int y,
    float (*lds)[64][65], int t) {
    const int c0 = x * 64;
    const int ar = t >> 4, ac = (t & 15) * 4;
    const int bc = t >> 3;
    const int rg = (t & 7) * 8;
#pragma unroll
    for (int it = 0; it < 2; ++it) {
        const int r0 = (y * 2 + it) * 64;
#pragma unroll
        for (int p = 0; p < 4; p++) {
            const int r = p * 16 + ar;
            const float4 v = *(const float4*)(src + (size_t)(r0 + r) * C + (c0 + ac));
            lds[it][r][ac] = v.x; lds[it][r][ac + 1] = v.y;
            lds[it][r][ac + 2] = v.z; lds[it][r][ac + 3] = v.w;
        }
    }
    __syncthreads();
#pragma unroll
    for (int it = 0; it < 2; ++it) {
        const int r0 = (y * 2 + it) * 64;
#pragma unroll
        for (int j = 0; j < 2; j++) {
            const int c = j * 32 + bc;
            unsigned w[4];
#pragma unroll
            for (int u = 0; u < 4; u++) {
                unsigned lo = (unsigned short)fb(lds[it][rg + 2 * u][c]);
                unsigned hi = (unsigned short)fb(lds[it][rg + 2 * u + 1][c]);
                w[u] = (hi << 16) | lo;
            }
            *(uint4*)((char*)dst + ((size_t)(c0 + c) * R + (r0 + rg)) * 2) = make_uint4(w[0], w[1], w[2], w[3]);
        }
    }
}

// ================= fused prep: W1 transpose || router+xconv || biascat =================
#define TGRID1 3328
#define RGRID  4352
#define PGRID  4456

__global__ __launch_bounds__(256) void prep_k(
    TPtr tp, bf16t* __restrict__ wt1,
    const float* __restrict__ hidden, const int* __restrict__ mode_ids,
    const float* __restrict__ rw, const float* __restrict__ rb,
    float* __restrict__ aux_logits, float* __restrict__ aux_idx, float* __restrict__ aux_probs,
    float* __restrict__ topk_p, int* __restrict__ topk_i, bf16t* __restrict__ xbf,
    const float* __restrict__ sb1, const float* __restrict__ mb1, const float* __restrict__ rb1,
    const float* __restrict__ sb2, const float* __restrict__ mb2, const float* __restrict__ rb2,
    float* __restrict__ B1c, float* __restrict__ B2c) {
    const int bid = blockIdx.x;
    const int t = threadIdx.x;

    if (bid < TGRID1) {
        __shared__ float lds[2][64][65];
        const size_t MSZ = (size_t)DIM * HID;
        const int z = bid >> 8, rem = bid & 255;
        const int x = (rem >> 3) & 31, y = rem & 7;     // 32 col-tiles x 8 row-pairs
        const float* src;
        if (z == 0)      src = tp.s_w1;
        else if (z < 5)  src = tp.m_w1 + (size_t)(z - 1) * MSZ;
        else             src = tp.r_w1 + (size_t)(z - 5) * MSZ;
        transpose_tile(src, wt1 + (size_t)z * MSZ, DIM, HID, x, y, lds, t);
        return;
    }

    if (bid < RGRID) {
        // ---------------- router: 4 tokens/block + fused f32->bf16 convert ----------------
        const int tok = (bid - TGRID1) * 4 + (t >> 6);
        const int lane = t & 63;
        const float* x = hidden + (size_t)tok * DIM;
        float acc[NEXP];
#pragma unroll
        for (int e = 0; e < NEXP; e++) acc[e] = 0.f;
#pragma unroll
        for (int i = 0; i < DIM / 64; i++) {
            int d = i * 64 + lane;
            float xv = x[d];
            xbf[(size_t)tok * DIM + d] = __float2bfloat16(xv);
            const float4* w = (const float4*)(rw + (size_t)d * NEXP);
            float4 w0 = w[0], w1 = w[1];
            acc[0] += xv * w0.x; acc[1] += xv * w0.y; acc[2] += xv * w0.z; acc[3] += xv * w0.w;
            acc[4] += xv * w1.x; acc[5] += xv * w1.y; acc[6] += xv * w1.z; acc[7] += xv * w1.w;
        }
#pragma unroll
        for (int off = 32; off >= 1; off >>= 1) {
#pragma unroll
            for (int e = 0; e < NEXP; e++) acc[e] += __shfl_down(acc[e], off, 64);
        }
        if (lane == 0) {
            float lg[NEXP], pb[NEXP];
            float mx = -1e30f;
#pragma unroll
            for (int e = 0; e < NEXP; e++) { lg[e] = acc[e] + rb[e]; mx = fmaxf(mx, lg[e]); }
            float s = 0.f;
#pragma unroll
            for (int e = 0; e < NEXP; e++) { pb[e] = expf(lg[e] - mx); s += pb[e]; }
            float inv = 1.f / s;
#pragma unroll
            for (int e = 0; e < NEXP; e++) { pb[e] *= inv; aux_logits[(size_t)tok * NEXP + e] = lg[e]; }
            int i1 = 0;
            for (int e = 1; e < NEXP; e++) if (pb[e] > pb[i1]) i1 = e;
            int i2 = (i1 == 0) ? 1 : 0;
            for (int e = 0; e < NEXP; e++) { if (e == i1) continue; if (pb[e] > pb[i2]) i2 = e; }
            aux_idx[tok * 2] = (float)i1;  aux_idx[tok * 2 + 1] = (float)i2;
            aux_probs[tok * 2] = pb[i1];   aux_probs[tok * 2 + 1] = pb[i2];
            topk_p[tok * 2] = pb[i1];      topk_p[tok * 2 + 1] = pb[i2];
            topk_i[tok * 2] = i1;          topk_i[tok * 2 + 1] = i2;
        }
        return;
    }

    // ---------------- biascat ----------------
    {
        const int i = (bid - RGRID) * 256 + t;
        if (i < NGRP * HID) {
            int g = i / HID, h = i % HID;
            B1c[i] = (g == 0) ? sb1[h] : (g < 5) ? mb1[(g - 1) * HID + h] : rb1[(g - 5) * HID + h];
        }
        if (i < NGRP * DIM) {
            int g = i / DIM, d = i % DIM;
            B2c[i] = (g == 0) ? sb2[d] : (g < 5) ? mb2[(g - 1) * DIM + d] : rb2[(g - 5) * DIM + d];
        }
    }
}

// ------- fused count+scan (single block, 1024 thr): ballot histogram -> cursors+tdesc; zero list pad -------
__global__ __launch_bounds__(1024) void group_k(
    const int* __restrict__ mode_ids, const int* __restrict__ topki,
    int* __restrict__ cursors, int4* __restrict__ tdesc, int* __restrict__ tcount,
    int* __restrict__ list) {
    __shared__ int cnts[12];
    const int lane = threadIdx.x & 63;
    const int wave = threadIdx.x >> 6;   // 0..15
    if (threadIdx.x < 12) cnts[threadIdx.x] = 0;
    // zero list pad [16384, SLOTS_PAD)
    if (threadIdx.x < SLOTS_PAD - 16384) list[16384 + threadIdx.x] = 0;
    __syncthreads();
    int local[12];
#pragma unroll
    for (int i = 0; i < 12; i++) local[i] = 0;
#pragma unroll
    for (int c = wave; c < NTOK / 64; c += 16) {
        const int t = c * 64 + lane;
        const int m  = mode_ids[t];
        const int e0 = topki[t * 2];
        const int e1 = topki[t * 2 + 1];
#pragma unroll
        for (int b = 0; b < 4; b++) local[b] += __popcll(__ballot(m == b));
#pragma unroll
        for (int b = 0; b < 8; b++) {
            local[4 + b] += __popcll(__ballot(e0 == b));
            local[4 + b] += __popcll(__ballot(e1 == b));
        }
    }
    if (lane == 0) {
#pragma unroll
        for (int i = 0; i < 12; i++) if (local[i]) atomicAdd(&cnts[i], local[i]);
    }
    __syncthreads();
    if (threadIdx.x == 0) {
        int nt = 0;
        auto emit = [&](int off, int c, int g) {
            for (int r0 = 0; r0 < c; r0 += 128) tdesc[nt++] = make_int4(off + r0, min(128, c - r0), g, 0);
        };
        emit(0, NTOK, 0);
        int off = NTOK;
        for (int m = 0; m < NMODE; m++) { cursors[m] = off; emit(off, cnts[m], 1 + m); off += cnts[m]; }
        off = 2 * NTOK;
        for (int e = 0; e < NEXP; e++) { cursors[NMODE + e] = off; emit(off, cnts[NMODE + e], 5 + e); off += cnts[NMODE + e]; }
        tcount[0] = nt;
    }
}

// ---------------- fill slot lists + inverse maps (wave-aggregated atomics) ----------------
__global__ void fill_k(const int* __restrict__ mode_ids, const int* __restrict__ topk_i,
                       int* __restrict__ cursors, int* __restrict__ list,
                       int* __restrict__ ms, int* __restrict__ r0s, int* __restrict__ r1s) {
    const int t = blockIdx.x * 256 + threadIdx.x;
    const int lane = threadIdx.x & 63;
    list[t] = t << 1;                                 // shared: identity
    const int m  = mode_ids[t];
    const int e0 = topk_i[t * 2], e1 = topk_i[t * 2 + 1];

    auto put = [&](int bin, bool pred, int payload, int* inv) {
        unsigned long long msk = __ballot(pred);
        if (msk == 0ull) return;
        int leader = __ffsll((unsigned long long)msk) - 1;
        int base = 0;
        if (lane == leader) base = atomicAdd(&cursors[bin], __popcll(msk));
        base = __shfl(base, leader, 64);
        if (pred) {
            int pos = base + __popcll(msk & ((1ull << lane) - 1ull));
            list[pos] = payload;
            inv[t] = pos;
        }
    };
#pragma unroll
    for (int b = 0; b < NMODE; b++) put(b, m == b, t << 1, ms);
#pragma unroll
    for (int b = 0; b < NEXP; b++) put(NMODE + b, e0 == b, t << 1, r0s);
#pragma unroll
    for (int b = 0; b < NEXP; b++) put(NMODE + b, e1 == b, (t << 1) | 1, r1s);
}

// ------- grouped FFN GEMM: 128x128 tile, BK=32, 4 waves, ring-3 LDS 48KB,
//         3 blocks/CU (m114 cross-block overlap), counted vmcnt(4), 1 barrier/K-tile.
//         STAGE 1 carries W2-transpose tail jobs (bid >= NWG) that backfill drain rounds. -------
// STAGE 1: Hbuf[slot] = gelu(Xbf[tok] @ W1[g] + b1[g])   K=1024, NK=32
// STAGE 2: Obuf[slot] = Hbuf[slot] @ W2[g] + b2[g]       K=2048, NK=64
#define W2GRID 3328
template <int STAGE>
__global__ __launch_bounds__(256, 3) void ffn_gemm_k(
    const bf16t* __restrict__ xbf,
    const bf16t* __restrict__ hbuf,
    const bf16t* __restrict__ wt,
    const float* __restrict__ bias,
    bf16t* __restrict__ obuf,
    const int* __restrict__ list,
    const int4* __restrict__ tdesc,
    const int* __restrict__ tcount,
    const float* __restrict__ w2s, const float* __restrict__ w2m, const float* __restrict__ w2r,
    bf16t* __restrict__ wt2o) {
    constexpr int K   = (STAGE == 1) ? DIM : HID;
    constexpr int N   = (STAGE == 1) ? HID : DIM;
    constexpr int NK  = K / 32;
    constexpr int NTN = N / 128;
    constexpr int NWG = NTN * MAXT;        // 2304 / 1152, divisible by 8

    __shared__ alignas(16) char smem[49152];   // GEMM: ring-3 As|Bs; transpose: f32 tiles

    if constexpr (STAGE == 1) {
        if (blockIdx.x >= NWG) {
            // ---- W2 transpose tail job (backfills GEMM1 drain) ----
            const int id2 = blockIdx.x - NWG;
            const size_t MSZ = (size_t)DIM * HID;
            const int z = id2 >> 8, rem = id2 & 255;
            const int x = rem >> 4, y = rem & 15;       // 16 col-tiles x 16 row-pairs
            const float* src;
            if (z == 0)      src = w2s;
            else if (z < 5)  src = w2m + (size_t)(z - 1) * MSZ;
            else             src = w2r + (size_t)(z - 5) * MSZ;
            transpose_tile(src, wt2o + (size_t)z * MSZ, HID, DIM, x, y,
                           (float (*)[64][65])smem, threadIdx.x);
            return;
        }
    }

    char* As = smem;                 // 3 * 8192
    char* Bs = smem + 24576;         // 3 * 8192

    const int lin = blockIdx.x;
    const int wg  = (lin & 7) * (NWG >> 3) + (lin >> 3);   // bijective XCD swizzle
    const int ntile = wg / MAXT;
    const int tix = wg - ntile * MAXT;
    if (tix >= tcount[0]) return;
    const int4 td = tdesc[tix];
    const int slot0 = td.x, rows = td.y, gidx = td.z;
    const int n0 = ntile * 128;

    const int tid  = threadIdx.x;    // 0..255
    const int lane = tid & 63;
    const int w    = tid >> 6;       // wave 0..3
    const int wm   = w >> 1, wn = w & 1;   // 2x2 wave grid, each 64x64 out

    // staging: wave w, load h in {0,1} covers 16 rows (w*2+h)*16 .. +16;
    // lane -> row +(lane>>2), chunk lane&3; source chunk inverse-swizzled.
    const bf16t* wbase = wt + (size_t)gidx * ((size_t)K * N);
    const bf16t* aP[2];
    const bf16t* bP[2];
#pragma unroll
    for (int h = 0; h < 2; h++) {
        const int r  = (w * 2 + h) * 16 + (lane >> 2);
        const int ce = (((lane & 3) ^ ((r >> 1) & 3)) << 3);
        if (STAGE == 1) aP[h] = xbf + (size_t)(list[slot0 + r] >> 1) * DIM + ce;
        else            aP[h] = hbuf + (size_t)(slot0 + r) * HID + ce;
        bP[h] = wbase + (size_t)(n0 + r) * K + ce;
    }

    auto stage = [&](int t) {
        char* la = As + (t % 3) * 8192 + (w * 2) * 1024 + lane * 16;
        char* lb = Bs + (t % 3) * 8192 + (w * 2) * 1024 + lane * 16;
        gload16(aP[0] + t * 32, la);
        gload16(aP[1] + t * 32, la + 1024);
        gload16(bP[0] + t * 32, lb);
        gload16(bP[1] + t * 32, lb + 1024);
    };

    f32x4 acc[4][4];
    const f32x4 zero = {0.f, 0.f, 0.f, 0.f};
#pragma unroll
    for (int i = 0; i < 4; i++)
#pragma unroll
        for (int j = 0; j < 4; j++) acc[i][j] = zero;

    const int lm = lane & 15;
    const int kc = lane >> 4;        // 16B chunk within 64B row

    stage(0); stage(1);              // depth-2 prefetch; 8 loads in flight

    for (int t = 0; t < NK; ++t) {
        const int cur = t % 3;
        // wait for tile t's 4 loads only; tile t+1's 4 stay in flight (never 0 until tail)
        if (t + 1 < NK) asm volatile("s_waitcnt vmcnt(4)" ::: "memory");
        else            asm volatile("s_waitcnt vmcnt(0)" ::: "memory");
        __builtin_amdgcn_s_barrier();    // buf[cur] resident for all waves (also closes WAR for ring-3)

        s16x8 av[4], bv[4];
#pragma unroll
        for (int i = 0; i < 4; i++) {
            const int Ra = wm * 64 + i * 16 + lm;
            av[i] = *(const s16x8*)(As + cur * 8192 + Ra * 64 + ((kc ^ ((Ra >> 1) & 3)) << 4));
            const int Rb = wn * 64 + i * 16 + lm;
            bv[i] = *(const s16x8*)(Bs + cur * 8192 + Rb * 64 + ((kc ^ ((Rb >> 1) & 3)) << 4));
        }
        if (t + 2 < NK) stage(t + 2);   // issue next prefetch under the MFMAs

        __builtin_amdgcn_s_setprio(1);
#pragma unroll
        for (int mi = 0; mi < 4; mi++)
#pragma unroll
            for (int ni = 0; ni < 4; ni++)
                acc[mi][ni] = __builtin_amdgcn_mfma_f32_16x16x32_bf16(av[mi], bv[ni], acc[mi][ni], 0, 0, 0);
        __builtin_amdgcn_s_setprio(0);
    }

    const int lr = lane >> 4, lc = lane & 15;
#pragma unroll
    for (int ni = 0; ni < 4; ni++) {
        const int col = n0 + wn * 64 + ni * 16 + lc;
        const float bvv = bias[gidx * N + col];
#pragma unroll
        for (int mi = 0; mi < 4; mi++) {
#pragma unroll
            for (int r = 0; r < 4; r++) {
                const int row = wm * 64 + mi * 16 + lr * 4 + r;
                if (row < rows) {
                    float v = acc[mi][ni][r] + bvv;
                    if (STAGE == 1) v = gelu_tanh(v);
                    obuf[(size_t)(slot0 + row) * N + col] = __float2bfloat16(v);
                }
            }
        }
    }
}

// ---------------- final gather-reduce: out[t] = sh + mode + p0*r0 + p1*r1 ----------------
__global__ void reduce_k(const bf16t* __restrict__ ob,
                         const int* __restrict__ ms, const int* __restrict__ r0s, const int* __restrict__ r1s,
                         const float* __restrict__ topkp, float* __restrict__ out) {
    const int t = blockIdx.x * 4 + (threadIdx.x >> 7);
    const int d = (threadIdx.x & 127) * 8;
    const s16x8 a = *(const s16x8*)(ob + (size_t)t * DIM + d);
    const s16x8 b = *(const s16x8*)(ob + (size_t)ms[t] * DIM + d);
    const s16x8 c = *(const s16x8*)(ob + (size_t)r0s[t] * DIM + d);
    const s16x8 e = *(const s16x8*)(ob + (size_t)r1s[t] * DIM + d);
    const float p0 = topkp[t * 2], p1 = topkp[t * 2 + 1];
    float o[8];
#pragma unroll
    for (int j = 0; j < 8; j++)
        o[j] = bf2f(a[j]) + bf2f(b[j]) + p0 * bf2f(c[j]) + p1 * bf2f(e[j]);
    float* dst = out + (size_t)t * DIM + d;
    *(float4*)dst = make_float4(o[0], o[1], o[2], o[3]);
    *(float4*)(dst + 4) = make_float4(o[4], o[5], o[6], o[7]);
}

extern "C" void kernel_launch(void* const* d_in, const int* in_sizes, int n_in,
                              void* d_out, int out_size, void* d_ws, size_t ws_size,
                              hipStream_t stream) {
    (void)in_sizes; (void)n_in; (void)out_size;
    if (ws_size < WS_NEED) return;

    const float* hidden   = (const float*)d_in[0];
    const int*   mode_ids = (const int*)d_in[1];
    const float* router_w = (const float*)d_in[2];
    const float* router_b = (const float*)d_in[3];
    TPtr tp;
    tp.s_w1 = (const float*)d_in[4];
    const float* s_b1 = (const float*)d_in[5];
    tp.s_w2 = (const float*)d_in[6];
    const float* s_b2 = (const float*)d_in[7];
    tp.m_w1 = (const float*)d_in[8];
    const float* m_b1 = (const float*)d_in[9];
    tp.m_w2 = (const float*)d_in[10];
    const float* m_b2 = (const float*)d_in[11];
    tp.r_w1 = (const float*)d_in[12];
    const float* r_b1 = (const float*)d_in[13];
    tp.r_w2 = (const float*)d_in[14];
    const float* r_b2 = (const float*)d_in[15];

    char* ws = (char*)d_ws;
    bf16t* WT1   = (bf16t*)(ws + OFF_WT1);
    bf16t* WT2   = (bf16t*)(ws + OFF_WT2);
    bf16t* Hbuf  = (bf16t*)(ws + OFF_HBUF);
    bf16t* Xbf   = (bf16t*)(ws + OFF_XBF);
    bf16t* Obuf  = (bf16t*)(ws + OFF_OBUF);
    float* B1c   = (float*)(ws + OFF_B1);
    float* B2c   = (float*)(ws + OFF_B2);
    float* topkp = (float*)(ws + OFF_TP);
    int*   topki = (int*)(ws + OFF_TI);
    int*   ms    = (int*)(ws + OFF_MS);
    int*   r0s   = (int*)(ws + OFF_R0S);
    int*   r1s   = (int*)(ws + OFF_R1S);
    int*   list  = (int*)(ws + OFF_LIST);
    int*   curs  = (int*)(ws + OFF_CUR);
    int*   tcnt  = (int*)(ws + OFF_TC);
    int4*  td    = (int4*)(ws + OFF_TD);

    float* out        = (float*)d_out;
    float* aux_logits = out + (size_t)NTOK * DIM;
    float* aux_idx    = aux_logits + (size_t)NTOK * NEXP;
    float* aux_probs  = aux_idx + (size_t)NTOK * 2;

    prep_k<<<PGRID, 256, 0, stream>>>(tp, WT1,
                                      hidden, mode_ids, router_w, router_b,
                                      aux_logits, aux_idx, aux_probs, topkp, topki, Xbf,
                                      s_b1, m_b1, r_b1, s_b2, m_b2, r_b2, B1c, B2c);
    group_k<<<1, 1024, 0, stream>>>(mode_ids, topki, curs, td, tcnt, list);
    fill_k<<<NTOK / 256, 256, 0, stream>>>(mode_ids, topki, curs, list, ms, r0s, r1s);
    ffn_gemm_k<1><<<(HID / 128) * MAXT + W2GRID, 256, 0, stream>>>(
        Xbf, Hbuf, WT1, B1c, Hbuf, list, td, tcnt, tp.s_w2, tp.m_w2, tp.r_w2, WT2);
    ffn_gemm_k<2><<<(DIM / 128) * MAXT, 256, 0, stream>>>(
        Xbf, Hbuf, WT2, B2c, Obuf, list, td, tcnt, nullptr, nullptr, nullptr, nullptr);
    reduce_k<<<NTOK / 4, 512, 0, stream>>>(Obuf, ms, r0s, r1s, topkp, out);
}

// Round 17
// 336.413 us; speedup vs baseline: 1.0419x; 1.0002x over previous
//
#include <hip/hip_runtime.h>
#include <hip/hip_bf16.h>

typedef __hip_bfloat16 bf16t;
using f32x4 = __attribute__((ext_vector_type(4))) float;
using s16x8 = __attribute__((ext_vector_type(8))) short;

#define NTOK 4096
#define DIM 1024
#define HID 2048
#define NEXP 8
#define NMODE 4
#define NGRP 13
#define SLOTS_PAD 16640   // 16384 + 256 pad for partial tiles
#define MAXT 144          // 128-row tiles over all groups (<=141)

// ---------------- workspace layout (bytes) ----------------
static constexpr size_t SZ_WT    = (size_t)NGRP * HID * DIM * 2;   // 54,525,952
static constexpr size_t OFF_WT1  = 0;
static constexpr size_t OFF_OBUF = 0;                               // overlay: WT1 dead before GEMM2
static constexpr size_t OFF_WT2  = OFF_WT1 + SZ_WT;
static constexpr size_t OFF_HBUF = OFF_WT2 + SZ_WT;
static constexpr size_t SZ_HBUF  = (size_t)SLOTS_PAD * HID * 2;
static constexpr size_t OFF_XBF  = OFF_HBUF + SZ_HBUF;
static constexpr size_t SZ_XBF   = (size_t)NTOK * DIM * 2;
static constexpr size_t OFF_B1   = OFF_XBF + SZ_XBF;
static constexpr size_t OFF_B2   = OFF_B1 + (size_t)NGRP * HID * 4;
static constexpr size_t OFF_TP   = OFF_B2 + (size_t)NGRP * DIM * 4;
static constexpr size_t OFF_TI   = OFF_TP + (size_t)NTOK * 2 * 4;
static constexpr size_t OFF_MS   = OFF_TI + (size_t)NTOK * 2 * 4;
static constexpr size_t OFF_R0S  = OFF_MS + (size_t)NTOK * 4;
static constexpr size_t OFF_R1S  = OFF_R0S + (size_t)NTOK * 4;
static constexpr size_t OFF_LIST = OFF_R1S + (size_t)NTOK * 4;
static constexpr size_t OFF_TC   = OFF_LIST + (size_t)SLOTS_PAD * 4;
static constexpr size_t OFF_TD   = OFF_TC + 16;
static constexpr size_t WS_NEED  = OFF_TD + (size_t)MAXT * 16;

static __device__ __forceinline__ short fb(float f) {
    bf16t h = __float2bfloat16(f);
    short s; __builtin_memcpy(&s, &h, 2); return s;
}
static __device__ __forceinline__ float bf2f(short s) {
    unsigned u = ((unsigned)(unsigned short)s) << 16;
    float f; __builtin_memcpy(&f, &u, 4); return f;
}

static __device__ __forceinline__ float fast_exp(float x) {
#if __has_builtin(__builtin_amdgcn_exp2f)
    return __builtin_amdgcn_exp2f(x * 1.4426950408889634f);
#else
    return exp2f(x * 1.4426950408889634f);
#endif
}
static __device__ __forceinline__ float fast_rcp(float x) {
#if __has_builtin(__builtin_amdgcn_rcpf)
    return __builtin_amdgcn_rcpf(x);
#else
    return 1.0f / x;
#endif
}
static __device__ __forceinline__ float gelu_tanh(float x) {
    float x2 = x * x;
    float u = 0.7978845608028654f * fmaf(0.044715f * x2, x, x);
    u = fminf(u, 15.0f);
    float t = fast_exp(2.0f * u);
    return x * t * fast_rcp(t + 1.0f);
}

typedef __attribute__((address_space(3))) void lds_void;
typedef const __attribute__((address_space(1))) void gbl_void;
static __device__ __forceinline__ void gload16(const void* g, void* l) {
    __builtin_amdgcn_global_load_lds((gbl_void*)g, (lds_void*)l, 16, 0, 0);
}

struct TPtr {
    const float* s_w1; const float* s_w2;
    const float* m_w1; const float* m_w2;
    const float* r_w1; const float* r_w2;
};

// 64x128 transpose+convert unit. smem >= 2*64*65*4 B. x = col-tile, y = row-pair.
static __device__ __forceinline__ void transpose_tile(
    const float* __restrict__ src, bf16t* __restrict__ dst, int R, int C, int x, int y,
    float (*lds)[64][65], int t) {
    const int c0 = x * 64;
    const int ar = t >> 4, ac = (t & 15) * 4;
    const int bc = t >> 3;
    const int rg = (t & 7) * 8;
#pragma unroll
    for (int it = 0; it < 2; ++it) {
        const int r0 = (y * 2 + it) * 64;
#pragma unroll
        for (int p = 0; p < 4; p++) {
            const int r = p * 16 + ar;
            const float4 v = *(const float4*)(src + (size_t)(r0 + r) * C + (c0 + ac));
            lds[it][r][ac] = v.x; lds[it][r][ac + 1] = v.y;
            lds[it][r][ac + 2] = v.z; lds[it][r][ac + 3] = v.w;
        }
    }
    __syncthreads();
#pragma unroll
    for (int it = 0; it < 2; ++it) {
        const int r0 = (y * 2 + it) * 64;
#pragma unroll
        for (int j = 0; j < 2; j++) {
            const int c = j * 32 + bc;
            unsigned w[4];
#pragma unroll
            for (int u = 0; u < 4; u++) {
                unsigned lo = (unsigned short)fb(lds[it][rg + 2 * u][c]);
                unsigned hi = (unsigned short)fb(lds[it][rg + 2 * u + 1][c]);
                w[u] = (hi << 16) | lo;
            }
            *(uint4*)((char*)dst + ((size_t)(c0 + c) * R + (r0 + rg)) * 2) = make_uint4(w[0], w[1], w[2], w[3]);
        }
    }
}

// ================= fused prep: W1 transpose || router+xconv || biascat =================
#define TGRID1 3328
#define RGRID  4352
#define PGRID  4456

__global__ __launch_bounds__(256) void prep_k(
    TPtr tp, bf16t* __restrict__ wt1,
    const float* __restrict__ hidden, const int* __restrict__ mode_ids,
    const float* __restrict__ rw, const float* __restrict__ rb,
    float* __restrict__ aux_logits, float* __restrict__ aux_idx, float* __restrict__ aux_probs,
    float* __restrict__ topk_p, int* __restrict__ topk_i, bf16t* __restrict__ xbf,
    const float* __restrict__ sb1, const float* __restrict__ mb1, const float* __restrict__ rb1,
    const float* __restrict__ sb2, const float* __restrict__ mb2, const float* __restrict__ rb2,
    float* __restrict__ B1c, float* __restrict__ B2c) {
    const int bid = blockIdx.x;
    const int t = threadIdx.x;

    if (bid < TGRID1) {
        __shared__ float lds[2][64][65];
        const size_t MSZ = (size_t)DIM * HID;
        const int z = bid >> 8, rem = bid & 255;
        const int x = (rem >> 3) & 31, y = rem & 7;     // 32 col-tiles x 8 row-pairs
        const float* src;
        if (z == 0)      src = tp.s_w1;
        else if (z < 5)  src = tp.m_w1 + (size_t)(z - 1) * MSZ;
        else             src = tp.r_w1 + (size_t)(z - 5) * MSZ;
        transpose_tile(src, wt1 + (size_t)z * MSZ, DIM, HID, x, y, lds, t);
        return;
    }

    if (bid < RGRID) {
        // ---------------- router: 4 tokens/block + fused f32->bf16 convert ----------------
        const int tok = (bid - TGRID1) * 4 + (t >> 6);
        const int lane = t & 63;
        const float* x = hidden + (size_t)tok * DIM;
        float acc[NEXP];
#pragma unroll
        for (int e = 0; e < NEXP; e++) acc[e] = 0.f;
#pragma unroll
        for (int i = 0; i < DIM / 64; i++) {
            int d = i * 64 + lane;
            float xv = x[d];
            xbf[(size_t)tok * DIM + d] = __float2bfloat16(xv);
            const float4* w = (const float4*)(rw + (size_t)d * NEXP);
            float4 w0 = w[0], w1 = w[1];
            acc[0] += xv * w0.x; acc[1] += xv * w0.y; acc[2] += xv * w0.z; acc[3] += xv * w0.w;
            acc[4] += xv * w1.x; acc[5] += xv * w1.y; acc[6] += xv * w1.z; acc[7] += xv * w1.w;
        }
#pragma unroll
        for (int off = 32; off >= 1; off >>= 1) {
#pragma unroll
            for (int e = 0; e < NEXP; e++) acc[e] += __shfl_down(acc[e], off, 64);
        }
        if (lane == 0) {
            float lg[NEXP], pb[NEXP];
            float mx = -1e30f;
#pragma unroll
            for (int e = 0; e < NEXP; e++) { lg[e] = acc[e] + rb[e]; mx = fmaxf(mx, lg[e]); }
            float s = 0.f;
#pragma unroll
            for (int e = 0; e < NEXP; e++) { pb[e] = expf(lg[e] - mx); s += pb[e]; }
            float inv = 1.f / s;
#pragma unroll
            for (int e = 0; e < NEXP; e++) { pb[e] *= inv; aux_logits[(size_t)tok * NEXP + e] = lg[e]; }
            int i1 = 0;
            for (int e = 1; e < NEXP; e++) if (pb[e] > pb[i1]) i1 = e;
            int i2 = (i1 == 0) ? 1 : 0;
            for (int e = 0; e < NEXP; e++) { if (e == i1) continue; if (pb[e] > pb[i2]) i2 = e; }
            aux_idx[tok * 2] = (float)i1;  aux_idx[tok * 2 + 1] = (float)i2;
            aux_probs[tok * 2] = pb[i1];   aux_probs[tok * 2 + 1] = pb[i2];
            topk_p[tok * 2] = pb[i1];      topk_p[tok * 2 + 1] = pb[i2];
            topk_i[tok * 2] = i1;          topk_i[tok * 2 + 1] = i2;
        }
        return;
    }

    // ---------------- biascat ----------------
    {
        const int i = (bid - RGRID) * 256 + t;
        if (i < NGRP * HID) {
            int g = i / HID, h = i % HID;
            B1c[i] = (g == 0) ? sb1[h] : (g < 5) ? mb1[(g - 1) * HID + h] : rb1[(g - 5) * HID + h];
        }
        if (i < NGRP * DIM) {
            int g = i / DIM, d = i % DIM;
            B2c[i] = (g == 0) ? sb2[d] : (g < 5) ? mb2[(g - 1) * DIM + d] : rb2[(g - 5) * DIM + d];
        }
    }
}

// ------- fused group+fill (single block, 1024 thr): histogram -> scan -> fill, cursors in LDS -------
__global__ __launch_bounds__(1024) void groupfill_k(
    const int* __restrict__ mode_ids, const int* __restrict__ topki,
    int4* __restrict__ tdesc, int* __restrict__ tcount,
    int* __restrict__ list,
    int* __restrict__ ms, int* __restrict__ r0s, int* __restrict__ r1s) {
    __shared__ int cnts[12];
    __shared__ int curs[12];
    const int lane = threadIdx.x & 63;
    const int wave = threadIdx.x >> 6;   // 0..15
    if (threadIdx.x < 12) cnts[threadIdx.x] = 0;
    if (threadIdx.x < SLOTS_PAD - 16384) list[16384 + threadIdx.x] = 0;   // zero pad
    __syncthreads();

    // ---- phase A: ballot histogram ----
    int local[12];
#pragma unroll
    for (int i = 0; i < 12; i++) local[i] = 0;
#pragma unroll
    for (int c = wave; c < NTOK / 64; c += 16) {
        const int t = c * 64 + lane;
        const int m  = mode_ids[t];
        const int e0 = topki[t * 2];
        const int e1 = topki[t * 2 + 1];
#pragma unroll
        for (int b = 0; b < 4; b++) local[b] += __popcll(__ballot(m == b));
#pragma unroll
        for (int b = 0; b < 8; b++) {
            local[4 + b] += __popcll(__ballot(e0 == b));
            local[4 + b] += __popcll(__ballot(e1 == b));
        }
    }
    if (lane == 0) {
#pragma unroll
        for (int i = 0; i < 12; i++) if (local[i]) atomicAdd(&cnts[i], local[i]);
    }
    __syncthreads();

    // ---- phase B: scan -> LDS cursors + tile descriptors ----
    if (threadIdx.x == 0) {
        int nt = 0;
        auto emit = [&](int off, int c, int g) {
            for (int r0 = 0; r0 < c; r0 += 128) tdesc[nt++] = make_int4(off + r0, min(128, c - r0), g, 0);
        };
        emit(0, NTOK, 0);
        int off = NTOK;
        for (int m = 0; m < NMODE; m++) { curs[m] = off; emit(off, cnts[m], 1 + m); off += cnts[m]; }
        off = 2 * NTOK;
        for (int e = 0; e < NEXP; e++) { curs[NMODE + e] = off; emit(off, cnts[NMODE + e], 5 + e); off += cnts[NMODE + e]; }
        tcount[0] = nt;
    }
    __syncthreads();

    // ---- phase C: fill (4 tokens/thread, wave-aggregated LDS atomics) ----
    auto put = [&](int bin, bool pred, int payload, int* inv, int t) {
        unsigned long long msk = __ballot(pred);
        if (msk == 0ull) return;
        int leader = __ffsll((unsigned long long)msk) - 1;
        int base = 0;
        if (lane == leader) base = atomicAdd(&curs[bin], __popcll(msk));
        base = __shfl(base, leader, 64);
        if (pred) {
            int pos = base + __popcll(msk & ((1ull << lane) - 1ull));
            list[pos] = payload;
            inv[t] = pos;
        }
    };
#pragma unroll
    for (int it = 0; it < 4; ++it) {
        const int t = it * 1024 + threadIdx.x;
        list[t] = t << 1;                             // shared: identity
        const int m  = mode_ids[t];
        const int e0 = topki[t * 2], e1 = topki[t * 2 + 1];
#pragma unroll
        for (int b = 0; b < NMODE; b++) put(b, m == b, t << 1, ms, t);
#pragma unroll
        for (int b = 0; b < NEXP; b++) put(NMODE + b, e0 == b, t << 1, r0s, t);
#pragma unroll
        for (int b = 0; b < NEXP; b++) put(NMODE + b, e1 == b, (t << 1) | 1, r1s, t);
    }
}

// ------- grouped FFN GEMM: 128x128 tile, BK=32, 4 waves, ring-3 LDS 48KB,
//         3 blocks/CU (m114 cross-block overlap), counted vmcnt(4), 1 barrier/K-tile.
//         STAGE 1 carries W2-transpose tail jobs (bid >= NWG) that backfill drain rounds. -------
// STAGE 1: Hbuf[slot] = gelu(Xbf[tok] @ W1[g] + b1[g])   K=1024, NK=32
// STAGE 2: Obuf[slot] = Hbuf[slot] @ W2[g] + b2[g]       K=2048, NK=64
#define W2GRID 3328
template <int STAGE>
__global__ __launch_bounds__(256, 3) void ffn_gemm_k(
    const bf16t* __restrict__ xbf,
    const bf16t* __restrict__ hbuf,
    const bf16t* __restrict__ wt,
    const float* __restrict__ bias,
    bf16t* __restrict__ obuf,
    const int* __restrict__ list,
    const int4* __restrict__ tdesc,
    const int* __restrict__ tcount,
    const float* __restrict__ w2s, const float* __restrict__ w2m, const float* __restrict__ w2r,
    bf16t* __restrict__ wt2o) {
    constexpr int K   = (STAGE == 1) ? DIM : HID;
    constexpr int N   = (STAGE == 1) ? HID : DIM;
    constexpr int NK  = K / 32;
    constexpr int NTN = N / 128;
    constexpr int NWG = NTN * MAXT;        // 2304 / 1152, divisible by 8

    __shared__ alignas(16) char smem[49152];   // GEMM: ring-3 As|Bs; transpose: f32 tiles

    if constexpr (STAGE == 1) {
        if (blockIdx.x >= NWG) {
            // ---- W2 transpose tail job (backfills GEMM1 drain) ----
            const int id2 = blockIdx.x - NWG;
            const size_t MSZ = (size_t)DIM * HID;
            const int z = id2 >> 8, rem = id2 & 255;
            const int x = rem >> 4, y = rem & 15;       // 16 col-tiles x 16 row-pairs
            const float* src;
            if (z == 0)      src = w2s;
            else if (z < 5)  src = w2m + (size_t)(z - 1) * MSZ;
            else             src = w2r + (size_t)(z - 5) * MSZ;
            transpose_tile(src, wt2o + (size_t)z * MSZ, HID, DIM, x, y,
                           (float (*)[64][65])smem, threadIdx.x);
            return;
        }
    }

    char* As = smem;                 // 3 * 8192
    char* Bs = smem + 24576;         // 3 * 8192

    const int lin = blockIdx.x;
    const int wg  = (lin & 7) * (NWG >> 3) + (lin >> 3);   // bijective XCD swizzle
    const int ntile = wg / MAXT;
    const int tix = wg - ntile * MAXT;
    if (tix >= tcount[0]) return;
    const int4 td = tdesc[tix];
    const int slot0 = td.x, rows = td.y, gidx = td.z;
    const int n0 = ntile * 128;

    const int tid  = threadIdx.x;    // 0..255
    const int lane = tid & 63;
    const int w    = tid >> 6;       // wave 0..3
    const int wm   = w >> 1, wn = w & 1;   // 2x2 wave grid, each 64x64 out

    // staging: wave w, load h in {0,1} covers 16 rows (w*2+h)*16 .. +16;
    // lane -> row +(lane>>2), chunk lane&3; source chunk inverse-swizzled.
    const bf16t* wbase = wt + (size_t)gidx * ((size_t)K * N);
    const bf16t* aP[2];
    const bf16t* bP[2];
#pragma unroll
    for (int h = 0; h < 2; h++) {
        const int r  = (w * 2 + h) * 16 + (lane >> 2);
        const int ce = (((lane & 3) ^ ((r >> 1) & 3)) << 3);
        if (STAGE == 1) aP[h] = xbf + (size_t)(list[slot0 + r] >> 1) * DIM + ce;
        else            aP[h] = hbuf + (size_t)(slot0 + r) * HID + ce;
        bP[h] = wbase + (size_t)(n0 + r) * K + ce;
    }

    auto stage = [&](int t) {
        char* la = As + (t % 3) * 8192 + (w * 2) * 1024 + lane * 16;
        char* lb = Bs + (t % 3) * 8192 + (w * 2) * 1024 + lane * 16;
        gload16(aP[0] + t * 32, la);
        gload16(aP[1] + t * 32, la + 1024);
        gload16(bP[0] + t * 32, lb);
        gload16(bP[1] + t * 32, lb + 1024);
    };

    f32x4 acc[4][4];
    const f32x4 zero = {0.f, 0.f, 0.f, 0.f};
#pragma unroll
    for (int i = 0; i < 4; i++)
#pragma unroll
        for (int j = 0; j < 4; j++) acc[i][j] = zero;

    const int lm = lane & 15;
    const int kc = lane >> 4;        // 16B chunk within 64B row

    stage(0); stage(1);              // depth-2 prefetch; 8 loads in flight

    for (int t = 0; t < NK; ++t) {
        const int cur = t % 3;
        // wait for tile t's 4 loads only; tile t+1's 4 stay in flight (never 0 until tail)
        if (t + 1 < NK) asm volatile("s_waitcnt vmcnt(4)" ::: "memory");
        else            asm volatile("s_waitcnt vmcnt(0)" ::: "memory");
        __builtin_amdgcn_s_barrier();    // buf[cur] resident for all waves (also closes WAR for ring-3)

        s16x8 av[4], bv[4];
#pragma unroll
        for (int i = 0; i < 4; i++) {
            const int Ra = wm * 64 + i * 16 + lm;
            av[i] = *(const s16x8*)(As + cur * 8192 + Ra * 64 + ((kc ^ ((Ra >> 1) & 3)) << 4));
            const int Rb = wn * 64 + i * 16 + lm;
            bv[i] = *(const s16x8*)(Bs + cur * 8192 + Rb * 64 + ((kc ^ ((Rb >> 1) & 3)) << 4));
        }
        if (t + 2 < NK) stage(t + 2);   // issue next prefetch under the MFMAs

        __builtin_amdgcn_s_setprio(1);
#pragma unroll
        for (int mi = 0; mi < 4; mi++)
#pragma unroll
            for (int ni = 0; ni < 4; ni++)
                acc[mi][ni] = __builtin_amdgcn_mfma_f32_16x16x32_bf16(av[mi], bv[ni], acc[mi][ni], 0, 0, 0);
        __builtin_amdgcn_s_setprio(0);
    }

    const int lr = lane >> 4, lc = lane & 15;
#pragma unroll
    for (int ni = 0; ni < 4; ni++) {
        const int col = n0 + wn * 64 + ni * 16 + lc;
        const float bvv = bias[gidx * N + col];
#pragma unroll
        for (int mi = 0; mi < 4; mi++) {
#pragma unroll
            for (int r = 0; r < 4; r++) {
                const int row = wm * 64 + mi * 16 + lr * 4 + r;
                if (row < rows) {
                    float v = acc[mi][ni][r] + bvv;
                    if (STAGE == 1) v = gelu_tanh(v);
                    obuf[(size_t)(slot0 + row) * N + col] = __float2bfloat16(v);
                }
            }
        }
    }
}

// ---------------- final gather-reduce: out[t] = sh + mode + p0*r0 + p1*r1 ----------------
__global__ void reduce_k(const bf16t* __restrict__ ob,
                         const int* __restrict__ ms, const int* __restrict__ r0s, const int* __restrict__ r1s,
                         const float* __restrict__ topkp, float* __restrict__ out) {
    const int t = blockIdx.x * 4 + (threadIdx.x >> 7);
    const int d = (threadIdx.x & 127) * 8;
    const s16x8 a = *(const s16x8*)(ob + (size_t)t * DIM + d);
    const s16x8 b = *(const s16x8*)(ob + (size_t)ms[t] * DIM + d);
    const s16x8 c = *(const s16x8*)(ob + (size_t)r0s[t] * DIM + d);
    const s16x8 e = *(const s16x8*)(ob + (size_t)r1s[t] * DIM + d);
    const float p0 = topkp[t * 2], p1 = topkp[t * 2 + 1];
    float o[8];
#pragma unroll
    for (int j = 0; j < 8; j++)
        o[j] = bf2f(a[j]) + bf2f(b[j]) + p0 * bf2f(c[j]) + p1 * bf2f(e[j]);
    float* dst = out + (size_t)t * DIM + d;
    *(float4*)dst = make_float4(o[0], o[1], o[2], o[3]);
    *(float4*)(dst + 4) = make_float4(o[4], o[5], o[6], o[7]);
}

extern "C" void kernel_launch(void* const* d_in, const int* in_sizes, int n_in,
                              void* d_out, int out_size, void* d_ws, size_t ws_size,
                              hipStream_t stream) {
    (void)in_sizes; (void)n_in; (void)out_size;
    if (ws_size < WS_NEED) return;

    const float* hidden   = (const float*)d_in[0];
    const int*   mode_ids = (const int*)d_in[1];
    const float* router_w = (const float*)d_in[2];
    const float* router_b = (const float*)d_in[3];
    TPtr tp;
    tp.s_w1 = (const float*)d_in[4];
    const float* s_b1 = (const float*)d_in[5];
    tp.s_w2 = (const float*)d_in[6];
    const float* s_b2 = (const float*)d_in[7];
    tp.m_w1 = (const float*)d_in[8];
    const float* m_b1 = (const float*)d_in[9];
    tp.m_w2 = (const float*)d_in[10];
    const float* m_b2 = (const float*)d_in[11];
    tp.r_w1 = (const float*)d_in[12];
    const float* r_b1 = (const float*)d_in[13];
    tp.r_w2 = (const float*)d_in[14];
    const float* r_b2 = (const float*)d_in[15];

    char* ws = (char*)d_ws;
    bf16t* WT1   = (bf16t*)(ws + OFF_WT1);
    bf16t* WT2   = (bf16t*)(ws + OFF_WT2);
    bf16t* Hbuf  = (bf16t*)(ws + OFF_HBUF);
    bf16t* Xbf   = (bf16t*)(ws + OFF_XBF);
    bf16t* Obuf  = (bf16t*)(ws + OFF_OBUF);
    float* B1c   = (float*)(ws + OFF_B1);
    float* B2c   = (float*)(ws + OFF_B2);
    float* topkp = (float*)(ws + OFF_TP);
    int*   topki = (int*)(ws + OFF_TI);
    int*   ms    = (int*)(ws + OFF_MS);
    int*   r0s   = (int*)(ws + OFF_R0S);
    int*   r1s   = (int*)(ws + OFF_R1S);
    int*   list  = (int*)(ws + OFF_LIST);
    int*   tcnt  = (int*)(ws + OFF_TC);
    int4*  td    = (int4*)(ws + OFF_TD);

    float* out        = (float*)d_out;
    float* aux_logits = out + (size_t)NTOK * DIM;
    float* aux_idx    = aux_logits + (size_t)NTOK * NEXP;
    float* aux_probs  = aux_idx + (size_t)NTOK * 2;

    prep_k<<<PGRID, 256, 0, stream>>>(tp, WT1,
                                      hidden, mode_ids, router_w, router_b,
                                      aux_logits, aux_idx, aux_probs, topkp, topki, Xbf,
                                      s_b1, m_b1, r_b1, s_b2, m_b2, r_b2, B1c, B2c);
    groupfill_k<<<1, 1024, 0, stream>>>(mode_ids, topki, td, tcnt, list, ms, r0s, r1s);
    ffn_gemm_k<1><<<(HID / 128) * MAXT + W2GRID, 256, 0, stream>>>(
        Xbf, Hbuf, WT1, B1c, Hbuf, list, td, tcnt, tp.s_w2, tp.m_w2, tp.r_w2, WT2);
    ffn_gemm_k<2><<<(DIM / 128) * MAXT, 256, 0, stream>>>(
        Xbf, Hbuf, WT2, B2c, Obuf, list, td, tcnt, nullptr, nullptr, nullptr, nullptr);
    reduce_k<<<NTOK / 4, 512, 0, stream>>>(Obuf, ms, r0s, r1s, topkp, out);
}